// Round 7
// baseline (234.451 us; speedup 1.0000x reference)
//
#include <hip/hip_runtime.h>
#include <stdint.h>

// MoleculeMultiHeadSelfAttention on MI355X (gfx950), round 7.
// B=2048, N=50, C=256, H=8, D=32.
// vs r5/6: each wave handles TWO full (b,h) with SAME h, adjacent b ->
// 2x independent chains/wave (latency hiding), shared Wa/Wm fragments &
// bias/mask/lambda; cold loads batched. LDS ordering via volatile accesses
// (in-order per-wave DS pipe) instead of s_waitcnt lgkmcnt(0) full drains.

typedef __attribute__((ext_vector_type(8))) short short8;
typedef __attribute__((ext_vector_type(4))) float f32x4;
typedef __attribute__((ext_vector_type(2))) unsigned u32x2;
typedef __attribute__((ext_vector_type(4))) unsigned u32x4;
typedef unsigned short u16;

#define L2E 1.4426950408889634f

__device__ __forceinline__ u16 f2bf(float f) {
  unsigned int u = __float_as_uint(f);
  u = (u + 0x7FFFu + ((u >> 16) & 1u)) >> 16;   // RNE; finite inputs
  return (u16)u;
}
__device__ __forceinline__ unsigned cvt_pk_bf16(float a, float b) {
  unsigned r;
  asm("v_cvt_pk_bf16_f32 %0, %1, %2" : "=v"(r) : "v"(a), "v"(b));
  return r;
}
__device__ __forceinline__ float exp2_fast(float x) {
#if __has_builtin(__builtin_amdgcn_exp2f)
  return __builtin_amdgcn_exp2f(x);
#else
  return __expf(x * 0.6931471805599453f);
#endif
}

// ---------------- merged casts (one launch) ----------------
__global__ __launch_bounds__(256) void cast_all(
    const float* __restrict__ adj, const float* __restrict__ mat,
    const float* __restrict__ Wq, const float* __restrict__ Wk,
    const float* __restrict__ Wa, const float* __restrict__ Wm,
    const float* __restrict__ ba, const float* __restrict__ bm,
    u16* __restrict__ da, u16* __restrict__ dm, u16* __restrict__ wqk,
    u16* __restrict__ wab, u16* __restrict__ wmb,
    float* __restrict__ bap, float* __restrict__ bmp, float* __restrict__ maskv,
    u16* __restrict__ qws, u16* __restrict__ kws) {
  const int blk = blockIdx.x, tid = threadIdx.x;
  if (blk < 2048) {
    const int total8 = (102416 * 64) / 8;
    for (int i8 = blk * 256 + tid; i8 < total8; i8 += 2048 * 256) {
      int r = i8 >> 3, c = (i8 & 7) * 8;
      short8 oa = (short8){0,0,0,0,0,0,0,0};
      short8 om = (short8){0,0,0,0,0,0,0,0};
      if (r < 102400) {
        size_t base = (size_t)r * 50;
#pragma unroll
        for (int p = 0; p < 4; ++p) {
          int col = c + 2 * p;
          if (col < 50) {
            float2 va = *(const float2*)(adj + base + col);
            float2 vm = *(const float2*)(mat + base + col);
            oa[2*p] = f2bf(va.x); oa[2*p+1] = f2bf(va.y);
            om[2*p] = f2bf(vm.x); om[2*p+1] = f2bf(vm.y);
          }
        }
      }
      *(short8*)(da + (size_t)i8 * 8) = oa;
      *(short8*)(dm + (size_t)i8 * 8) = om;
    }
  } else if (blk < 2112) {
    int idx8 = (blk - 2048) * 256 + tid;
    int r = idx8 >> 5, c = (idx8 & 31) * 8;
    const float* src = (r < 256) ? (Wq + (size_t)r * 256 + c)
                                 : (Wk + (size_t)(r - 256) * 256 + c);
    float4 v0 = *(const float4*)(src);
    float4 v1 = *(const float4*)(src + 4);
    short8 o;
    o[0] = f2bf(v0.x); o[1] = f2bf(v0.y); o[2] = f2bf(v0.z); o[3] = f2bf(v0.w);
    o[4] = f2bf(v1.x); o[5] = f2bf(v1.y); o[6] = f2bf(v1.z); o[7] = f2bf(v1.w);
    *(short8*)(wqk + (size_t)idx8 * 8) = o;
  } else if (blk < 2216) {
    int idx = (blk - 2112) * 256 + tid;
    int r = idx >> 6, c = idx & 63;
    float va = 0.f, vm = 0.f;
    if (r < 400 && c < 50) { va = Wa[r * 50 + c]; vm = Wm[r * 50 + c]; }
    wab[idx] = f2bf(va); wmb[idx] = f2bf(vm);
  } else {
    short8 z = (short8){0,0,0,0,0,0,0,0};
    *(short8*)(qws + (size_t)819200 * 32 + tid * 8) = z;
    *(short8*)(kws + (size_t)819200 * 32 + tid * 8) = z;
#pragma unroll
    for (int j = 0; j < 2; ++j) {
      int idx = tid + 256 * j;
      int hh = idx >> 6, m = idx & 63;
      bap[idx] = (m < 50) ? ba[hh * 50 + m] * L2E : -1.0e30f;
      bmp[idx] = (m < 50) ? bm[hh * 50 + m] * L2E : -1.0e30f;
    }
    if (tid < 64) maskv[tid] = (tid < 50) ? 0.f : -1.0e30f;
  }
}

// ---------------- projection GEMM (unchanged) ----------------
__global__ __launch_bounds__(256) void proj_kernel(
    const float* __restrict__ x, const u16* __restrict__ wqk,
    const float* __restrict__ bq, const float* __restrict__ bk,
    u16* __restrict__ qws, u16* __restrict__ kws) {
  __shared__ char xa[64 * 512];
  __shared__ char wb[64 * 512];
  const int tid = threadIdx.x;
  const int m0 = blockIdx.x * 64;

#pragma unroll
  for (int t = 0; t < 16; ++t) {
    int idx = tid + t * 256;
    int r = idx >> 6, c4 = idx & 63;
    float4 v = *(const float4*)(x + (size_t)(m0 + r) * 256 + c4 * 4);
    unsigned long long pk = (unsigned long long)f2bf(v.x)
                          | ((unsigned long long)f2bf(v.y) << 16)
                          | ((unsigned long long)f2bf(v.z) << 32)
                          | ((unsigned long long)f2bf(v.w) << 48);
    int byte = (r * 512 + c4 * 8) ^ ((r & 7) << 4);
    *(unsigned long long*)(xa + byte) = pk;
  }
  __syncthreads();

  const int w = tid >> 6, l = tid & 63, lo = l & 15, g = l >> 4;
  short8 a[8];
  const int ra = 16 * w + lo;
#pragma unroll
  for (int ks = 0; ks < 8; ++ks)
    a[ks] = *(const short8*)(xa + ((ra * 512 + ks * 64 + g * 16) ^ ((ra & 7) << 4)));
  size_t mb[4];
#pragma unroll
  for (int i = 0; i < 4; ++i) {
    int m = m0 + 16 * w + 4 * g + i;
    int b = m / 50;
    int n = m - 50 * b;
    mb[i] = (size_t)b * 12800 + (size_t)n * 32;
  }

  for (int nt = 0; nt < 8; ++nt) {
    __syncthreads();
#pragma unroll
    for (int t = 0; t < 8; ++t) {
      int idx = tid + t * 256;
      int r = idx >> 5, c8 = idx & 31;
      short8 v = *(const short8*)(wqk + (size_t)(nt * 64 + r) * 256 + c8 * 8);
      int byte = (r * 512 + c8 * 16) ^ ((r & 7) << 4);
      *(short8*)(wb + byte) = v;
    }
    __syncthreads();

    f32x4 acc[4];
#pragma unroll
    for (int tj = 0; tj < 4; ++tj) acc[tj] = (f32x4){0.f, 0.f, 0.f, 0.f};
#pragma unroll
    for (int ks = 0; ks < 8; ++ks) {
#pragma unroll
      for (int tj = 0; tj < 4; ++tj) {
        int rb = 16 * tj + lo;
        short8 bb = *(const short8*)(wb + ((rb * 512 + ks * 64 + g * 16) ^ ((rb & 7) << 4)));
        acc[tj] = __builtin_amdgcn_mfma_f32_16x16x32_bf16(a[ks], bb, acc[tj], 0, 0, 0);
      }
    }
    const int n0 = nt * 64;
#pragma unroll
    for (int tj = 0; tj < 4; ++tj) {
      int j = n0 + 16 * tj + lo;
      int jj = j & 255;
      float bias = (j < 256) ? bq[jj] : bk[jj];
      u16* dst = (j < 256) ? qws : kws;
      int hh = jj >> 5, d = jj & 31;
#pragma unroll
      for (int i = 0; i < 4; ++i)
        dst[mb[i] + (size_t)hh * 1600 + d] = f2bf(acc[tj][i] + bias);
    }
  }
}

// ---------------- fused attention: 2 full (b,h) per wave, same h ----------------

// softmax for one 16-col tile: exp2(fma) -> tree+2 shfl sum -> scale -> pack ->
// volatile P writes (ordering vs subsequent volatile reads via in-order DS pipe)
__device__ __forceinline__ void sm_store(
    f32x4 (&S)[4], const f32x4 (&bml)[4], float sl2e, float lam,
    u16* pb, int buf, int lo, int g) {
  float p[4][4];
#pragma unroll
  for (int ti = 0; ti < 4; ++ti)
#pragma unroll
    for (int i = 0; i < 4; ++i)
      p[ti][i] = exp2_fast(S[ti][i] * sl2e + bml[ti][i]);
  float t0 = (p[0][0] + p[0][1]) + (p[0][2] + p[0][3]);
  float t1 = (p[1][0] + p[1][1]) + (p[1][2] + p[1][3]);
  float t2 = (p[2][0] + p[2][1]) + (p[2][2] + p[2][3]);
  float t3 = (p[3][0] + p[3][1]) + (p[3][2] + p[3][3]);
  float sum = (t0 + t1) + (t2 + t3);
  sum += __shfl_xor(sum, 16);
  sum += __shfl_xor(sum, 32);
  float r = lam * __builtin_amdgcn_rcpf(sum);
#pragma unroll
  for (int ti = 0; ti < 4; ++ti) {
    u32x2 pk;
    pk.x = cvt_pk_bf16(p[ti][0] * r, p[ti][1] * r);
    pk.y = cvt_pk_bf16(p[ti][2] * r, p[ti][3] * r);
    *(volatile u32x2*)(pb + buf * 1152 + lo * 72 + 16 * ti + 4 * g) = pk;
  }
}

__device__ __forceinline__ void pv_acc(
    const u16* pb, int buf, const short8 (&vbS)[2][2], f32x4 (&Otj)[2],
    int lo, int g) {
#pragma unroll
  for (int ks = 0; ks < 2; ++ks) {
    u32x4 t = *(const volatile u32x4*)(pb + buf * 1152 + lo * 72 + ks * 32 + g * 8);
    short8 pa = __builtin_bit_cast(short8, t);
#pragma unroll
    for (int tjv = 0; tjv < 2; ++tjv)
      Otj[tjv] = __builtin_amdgcn_mfma_f32_16x16x32_bf16(pa, vbS[tjv][ks], Otj[tjv], 0, 0, 0);
  }
}

__global__ __launch_bounds__(256, 2) void attn_kernel(
    const u16* __restrict__ qws, const u16* __restrict__ kws,
    const u16* __restrict__ adjb, const u16* __restrict__ matb,
    const u16* __restrict__ wab, const u16* __restrict__ wmb,
    const float* __restrict__ bap, const float* __restrict__ bmp,
    const float* __restrict__ maskv,
    const float* __restrict__ lambdas, float* __restrict__ out) {
  __shared__ u16 smem[4][2][2304];   // [wave][chain]: kT[32][72] overlaid by P dbuf
  const int tid = threadIdx.x;
  const int w = tid >> 6, l = tid & 63, lo = l & 15, g = l >> 4;
  const int wid = blockIdx.x * 4 + w;          // [0, 8192)
  const int h = wid & 7;
  const int bp = wid >> 3;                     // [0, 1024)
  const int b0 = 2 * bp, b1 = 2 * bp + 1;
  const int bh0 = b0 * 8 + h, bh1 = b1 * 8 + h;
  u16* pb0 = smem[w][0];
  u16* pb1 = smem[w][1];

  // softmax(lambdas[h]) — shared by both chains
  float la = lambdas[h * 3 + 0], lb = lambdas[h * 3 + 1], lc = lambdas[h * 3 + 2];
  float lmx = fmaxf(la, fmaxf(lb, lc));
  float e0 = __expf(la - lmx), e1 = __expf(lb - lmx), e2 = __expf(lc - lmx);
  float einv = 1.f / (e0 + e1 + e2);
  float lam0 = e0 * einv, lam1 = e1 * einv, lam2 = e2 * einv;

  // ---- stage kT (V^T) for both chains: [32 d][72 m], zero pad m>=50 ----
  {
    const u16* kr0 = kws + (size_t)bh0 * 1600 + (size_t)l * 32;
    const u16* kr1 = kws + (size_t)bh1 * 1600 + (size_t)l * 32;
#pragma unroll
    for (int ch = 0; ch < 4; ++ch) {
      short8 v0 = (short8){0,0,0,0,0,0,0,0};
      short8 v1 = (short8){0,0,0,0,0,0,0,0};
      if (l < 50) {
        v0 = *(const short8*)(kr0 + ch * 8);
        v1 = *(const short8*)(kr1 + ch * 8);
      }
#pragma unroll
      for (int jj = 0; jj < 8; ++jj) {
        *(volatile u16*)(pb0 + (ch * 8 + jj) * 72 + l) = (u16)v0[jj];
        *(volatile u16*)(pb1 + (ch * 8 + jj) * 72 + l) = (u16)v1[jj];
      }
    }
  }
  // hoist V^T fragments (kT regions are reused as P afterwards)
  short8 vb0[2][2], vb1[2][2];
#pragma unroll
  for (int tjv = 0; tjv < 2; ++tjv)
#pragma unroll
    for (int ks = 0; ks < 2; ++ks) {
      u32x4 t0 = *(const volatile u32x4*)(pb0 + (lo + 16 * tjv) * 72 + ks * 32 + g * 8);
      u32x4 t1 = *(const volatile u32x4*)(pb1 + (lo + 16 * tjv) * 72 + ks * 32 + g * 8);
      vb0[tjv][ks] = __builtin_bit_cast(short8, t0);
      vb1[tjv][ks] = __builtin_bit_cast(short8, t1);
    }

  f32x4 O[2][4][2];
#pragma unroll
  for (int s = 0; s < 2; ++s)
#pragma unroll
    for (int tj = 0; tj < 4; ++tj)
#pragma unroll
      for (int tjv = 0; tjv < 2; ++tjv) O[s][tj][tjv] = (f32x4){0.f,0.f,0.f,0.f};

  // ---- phase 1: S^T = K·Q^T, scale (1/16)·log2e ----
  {
    short8 af0[4], af1[4];
#pragma unroll
    for (int ti = 0; ti < 4; ++ti) {
      af0[ti] = *(const short8*)(kws + (size_t)bh0 * 1600 + (size_t)(lo + 16 * ti) * 32 + g * 8);
      af1[ti] = *(const short8*)(kws + (size_t)bh1 * 1600 + (size_t)(lo + 16 * ti) * 32 + g * 8);
    }
    f32x4 bml[4];
#pragma unroll
    for (int ti = 0; ti < 4; ++ti)
      bml[ti] = *(const f32x4*)(maskv + 16 * ti + 4 * g);
#pragma unroll
    for (int tj = 0; tj < 4; ++tj) {
      short8 qf0 = *(const short8*)(qws + (size_t)bh0 * 1600 + (size_t)(lo + 16 * tj) * 32 + g * 8);
      short8 qf1 = *(const short8*)(qws + (size_t)bh1 * 1600 + (size_t)(lo + 16 * tj) * 32 + g * 8);
      f32x4 S0[4], S1[4];
#pragma unroll
      for (int ti = 0; ti < 4; ++ti) { S0[ti] = (f32x4){0,0,0,0}; S1[ti] = (f32x4){0,0,0,0}; }
#pragma unroll
      for (int ti = 0; ti < 4; ++ti) {
        S0[ti] = __builtin_amdgcn_mfma_f32_16x16x32_bf16(af0[ti], qf0, S0[ti], 0, 0, 0);
        S1[ti] = __builtin_amdgcn_mfma_f32_16x16x32_bf16(af1[ti], qf1, S1[ti], 0, 0, 0);
      }
      sm_store(S0, bml, 0.0625f * L2E, lam0, pb0, tj & 1, lo, g);
      sm_store(S1, bml, 0.0625f * L2E, lam0, pb1, tj & 1, lo, g);
      pv_acc(pb0, tj & 1, vb0, O[0][tj], lo, g);
      pv_acc(pb1, tj & 1, vb1, O[1][tj], lo, g);
    }
  }
  // ---- phases 2 & 3: adj / matrix transforms (Wa/Wm fragments shared) ----
#pragma unroll
  for (int ph = 0; ph < 2; ++ph) {
    const u16* aBase = (ph == 0 ? wab : wmb) + (size_t)h * 3200;
    const u16* bB0 = (ph == 0 ? adjb : matb) + (size_t)b0 * 3200;
    const u16* bB1 = (ph == 0 ? adjb : matb) + (size_t)b1 * 3200;
    const float* bPad = (ph == 0 ? bap : bmp) + h * 64;
    float lamp = (ph == 0) ? lam1 : lam2;

    short8 afw[4][2];
#pragma unroll
    for (int ti = 0; ti < 4; ++ti)
#pragma unroll
      for (int ks = 0; ks < 2; ++ks)
        afw[ti][ks] = *(const short8*)(aBase + (size_t)(lo + 16 * ti) * 64 + ks * 32 + g * 8);
    f32x4 bml[4];
#pragma unroll
    for (int ti = 0; ti < 4; ++ti)
      bml[ti] = *(const f32x4*)(bPad + 16 * ti + 4 * g);

#pragma unroll
    for (int tj = 0; tj < 4; ++tj) {
      short8 bf0[2], bf1[2];
#pragma unroll
      for (int ks = 0; ks < 2; ++ks) {
        bf0[ks] = *(const short8*)(bB0 + (size_t)(lo + 16 * tj) * 64 + ks * 32 + g * 8);
        bf1[ks] = *(const short8*)(bB1 + (size_t)(lo + 16 * tj) * 64 + ks * 32 + g * 8);
      }
      f32x4 S0[4], S1[4];
#pragma unroll
      for (int ti = 0; ti < 4; ++ti) { S0[ti] = (f32x4){0,0,0,0}; S1[ti] = (f32x4){0,0,0,0}; }
#pragma unroll
      for (int ti = 0; ti < 4; ++ti) {
        S0[ti] = __builtin_amdgcn_mfma_f32_16x16x32_bf16(afw[ti][0], bf0[0], S0[ti], 0, 0, 0);
        S1[ti] = __builtin_amdgcn_mfma_f32_16x16x32_bf16(afw[ti][0], bf1[0], S1[ti], 0, 0, 0);
      }
#pragma unroll
      for (int ti = 0; ti < 4; ++ti) {
        S0[ti] = __builtin_amdgcn_mfma_f32_16x16x32_bf16(afw[ti][1], bf0[1], S0[ti], 0, 0, 0);
        S1[ti] = __builtin_amdgcn_mfma_f32_16x16x32_bf16(afw[ti][1], bf1[1], S1[ti], 0, 0, 0);
      }
      sm_store(S0, bml, L2E, lamp, pb0, tj & 1, lo, g);
      sm_store(S1, bml, L2E, lamp, pb1, tj & 1, lo, g);
      pv_acc(pb0, tj & 1, vb0, O[0][tj], lo, g);
      pv_acc(pb1, tj & 1, vb1, O[1][tj], lo, g);
    }
  }

  // ---- epilogue: out[b][n][h*32+d], f32, both chains ----
#pragma unroll
  for (int s = 0; s < 2; ++s) {
    float* ob = out + (size_t)(s ? b1 : b0) * 12800 + h * 32;
#pragma unroll
    for (int tj = 0; tj < 4; ++tj)
#pragma unroll
      for (int i = 0; i < 4; ++i) {
        int n = 16 * tj + 4 * g + i;
        if (n < 50) {
#pragma unroll
          for (int tjv = 0; tjv < 2; ++tjv)
            ob[(size_t)n * 256 + 16 * tjv + lo] = O[s][tj][tjv][i];
        }
      }
  }
}

extern "C" void kernel_launch(void* const* d_in, const int* in_sizes, int n_in,
                              void* d_out, int out_size, void* d_ws, size_t ws_size,
                              hipStream_t stream) {
  const float* x       = (const float*)d_in[0];
  const float* adj     = (const float*)d_in[1];
  const float* mat     = (const float*)d_in[2];
  const float* Wq      = (const float*)d_in[3];
  const float* bq      = (const float*)d_in[4];
  const float* Wk      = (const float*)d_in[5];
  const float* bk      = (const float*)d_in[6];
  const float* Wa      = (const float*)d_in[7];
  const float* ba      = (const float*)d_in[8];
  const float* Wm      = (const float*)d_in[9];
  const float* bm      = (const float*)d_in[10];
  const float* lambdas = (const float*)d_in[11];
  float* out = (float*)d_out;

  char* ws = (char*)d_ws;
  u16* wqk    = (u16*)ws; ws += (size_t)512 * 256 * 2;
  u16* wab    = (u16*)ws; ws += (size_t)416 * 64 * 2;
  u16* wmb    = (u16*)ws; ws += (size_t)416 * 64 * 2;
  float* bap  = (float*)ws; ws += (size_t)512 * 4;
  float* bmp  = (float*)ws; ws += (size_t)512 * 4;
  float* mskv = (float*)ws; ws += (size_t)64 * 4;
  u16* adjb   = (u16*)ws; ws += (size_t)102416 * 64 * 2;
  u16* matb   = (u16*)ws; ws += (size_t)102416 * 64 * 2;
  u16* qws    = (u16*)ws; ws += (size_t)819264 * 32 * 2;  // 16384*50 + 64 slack
  u16* kws    = (u16*)ws; ws += (size_t)819264 * 32 * 2;

  cast_all<<<2217, 256, 0, stream>>>(adj, mat, Wq, Wk, Wa, Wm, ba, bm,
                                     adjb, matb, wqk, wab, wmb,
                                     bap, bmp, mskv, qws, kws);
  proj_kernel<<<1600, 256, 0, stream>>>(x, wqk, bq, bk, qws, kws);
  attn_kernel<<<2048, 256, 0, stream>>>(qws, kws, adjb, matb, wab, wmb,
                                        bap, bmp, mskv, lambdas, out);
}

// Round 8
// 232.373 us; speedup vs baseline: 1.0089x; 1.0089x over previous
//
#include <hip/hip_runtime.h>
#include <stdint.h>

// MoleculeMultiHeadSelfAttention on MI355X (gfx950), round 8.
// B=2048, N=50, C=256, H=8, D=32.
// Base = r3 (best attn 119us) + explicit phase-ahead prefetch of global
// fragments (T14: the per-tile qf/bf loads were ~900cy HBM misses serialized
// in the chain), volatile-LDS ordering (no lgkmcnt drains), no VGPR cap.

typedef __attribute__((ext_vector_type(8))) short short8;
typedef __attribute__((ext_vector_type(4))) float f32x4;
typedef __attribute__((ext_vector_type(2))) unsigned u32x2;
typedef __attribute__((ext_vector_type(4))) unsigned u32x4;
typedef unsigned short u16;

#define L2E 1.4426950408889634f

__device__ __forceinline__ u16 f2bf(float f) {
  unsigned int u = __float_as_uint(f);
  u = (u + 0x7FFFu + ((u >> 16) & 1u)) >> 16;   // RNE; finite inputs
  return (u16)u;
}
__device__ __forceinline__ unsigned cvt_pk_bf16(float a, float b) {
  unsigned r;
  asm("v_cvt_pk_bf16_f32 %0, %1, %2" : "=v"(r) : "v"(a), "v"(b));
  return r;
}
__device__ __forceinline__ float exp2_fast(float x) {
#if __has_builtin(__builtin_amdgcn_exp2f)
  return __builtin_amdgcn_exp2f(x);
#else
  return __expf(x * 0.6931471805599453f);
#endif
}

// ---------------- merged casts (one launch; same as r5) ----------------
__global__ __launch_bounds__(256) void cast_all(
    const float* __restrict__ adj, const float* __restrict__ mat,
    const float* __restrict__ Wq, const float* __restrict__ Wk,
    const float* __restrict__ Wa, const float* __restrict__ Wm,
    const float* __restrict__ ba, const float* __restrict__ bm,
    u16* __restrict__ da, u16* __restrict__ dm, u16* __restrict__ wqk,
    u16* __restrict__ wab, u16* __restrict__ wmb,
    float* __restrict__ bap, float* __restrict__ bmp, float* __restrict__ maskv,
    u16* __restrict__ qws, u16* __restrict__ kws) {
  const int blk = blockIdx.x, tid = threadIdx.x;
  if (blk < 2048) {
    const int total8 = (102416 * 64) / 8;
    for (int i8 = blk * 256 + tid; i8 < total8; i8 += 2048 * 256) {
      int r = i8 >> 3, c = (i8 & 7) * 8;
      short8 oa = (short8){0,0,0,0,0,0,0,0};
      short8 om = (short8){0,0,0,0,0,0,0,0};
      if (r < 102400) {
        size_t base = (size_t)r * 50;
#pragma unroll
        for (int p = 0; p < 4; ++p) {
          int col = c + 2 * p;
          if (col < 50) {
            float2 va = *(const float2*)(adj + base + col);
            float2 vm = *(const float2*)(mat + base + col);
            oa[2*p] = f2bf(va.x); oa[2*p+1] = f2bf(va.y);
            om[2*p] = f2bf(vm.x); om[2*p+1] = f2bf(vm.y);
          }
        }
      }
      *(short8*)(da + (size_t)i8 * 8) = oa;
      *(short8*)(dm + (size_t)i8 * 8) = om;
    }
  } else if (blk < 2112) {
    int idx8 = (blk - 2048) * 256 + tid;
    int r = idx8 >> 5, c = (idx8 & 31) * 8;
    const float* src = (r < 256) ? (Wq + (size_t)r * 256 + c)
                                 : (Wk + (size_t)(r - 256) * 256 + c);
    float4 v0 = *(const float4*)(src);
    float4 v1 = *(const float4*)(src + 4);
    short8 o;
    o[0] = f2bf(v0.x); o[1] = f2bf(v0.y); o[2] = f2bf(v0.z); o[3] = f2bf(v0.w);
    o[4] = f2bf(v1.x); o[5] = f2bf(v1.y); o[6] = f2bf(v1.z); o[7] = f2bf(v1.w);
    *(short8*)(wqk + (size_t)idx8 * 8) = o;
  } else if (blk < 2216) {
    int idx = (blk - 2112) * 256 + tid;
    int r = idx >> 6, c = idx & 63;
    float va = 0.f, vm = 0.f;
    if (r < 400 && c < 50) { va = Wa[r * 50 + c]; vm = Wm[r * 50 + c]; }
    wab[idx] = f2bf(va); wmb[idx] = f2bf(vm);
  } else {
    short8 z = (short8){0,0,0,0,0,0,0,0};
    *(short8*)(qws + (size_t)819200 * 32 + tid * 8) = z;
    *(short8*)(kws + (size_t)819200 * 32 + tid * 8) = z;
#pragma unroll
    for (int j = 0; j < 2; ++j) {
      int idx = tid + 256 * j;
      int hh = idx >> 6, m = idx & 63;
      bap[idx] = (m < 50) ? ba[hh * 50 + m] * L2E : -1.0e30f;
      bmp[idx] = (m < 50) ? bm[hh * 50 + m] * L2E : -1.0e30f;
    }
    if (tid < 64) maskv[tid] = (tid < 50) ? 0.f : -1.0e30f;
  }
}

// ---------------- projection GEMM (unchanged) ----------------
__global__ __launch_bounds__(256) void proj_kernel(
    const float* __restrict__ x, const u16* __restrict__ wqk,
    const float* __restrict__ bq, const float* __restrict__ bk,
    u16* __restrict__ qws, u16* __restrict__ kws) {
  __shared__ char xa[64 * 512];
  __shared__ char wb[64 * 512];
  const int tid = threadIdx.x;
  const int m0 = blockIdx.x * 64;

#pragma unroll
  for (int t = 0; t < 16; ++t) {
    int idx = tid + t * 256;
    int r = idx >> 6, c4 = idx & 63;
    float4 v = *(const float4*)(x + (size_t)(m0 + r) * 256 + c4 * 4);
    unsigned long long pk = (unsigned long long)f2bf(v.x)
                          | ((unsigned long long)f2bf(v.y) << 16)
                          | ((unsigned long long)f2bf(v.z) << 32)
                          | ((unsigned long long)f2bf(v.w) << 48);
    int byte = (r * 512 + c4 * 8) ^ ((r & 7) << 4);
    *(unsigned long long*)(xa + byte) = pk;
  }
  __syncthreads();

  const int w = tid >> 6, l = tid & 63, lo = l & 15, g = l >> 4;
  short8 a[8];
  const int ra = 16 * w + lo;
#pragma unroll
  for (int ks = 0; ks < 8; ++ks)
    a[ks] = *(const short8*)(xa + ((ra * 512 + ks * 64 + g * 16) ^ ((ra & 7) << 4)));
  size_t mb[4];
#pragma unroll
  for (int i = 0; i < 4; ++i) {
    int m = m0 + 16 * w + 4 * g + i;
    int b = m / 50;
    int n = m - 50 * b;
    mb[i] = (size_t)b * 12800 + (size_t)n * 32;
  }

  for (int nt = 0; nt < 8; ++nt) {
    __syncthreads();
#pragma unroll
    for (int t = 0; t < 8; ++t) {
      int idx = tid + t * 256;
      int r = idx >> 5, c8 = idx & 31;
      short8 v = *(const short8*)(wqk + (size_t)(nt * 64 + r) * 256 + c8 * 8);
      int byte = (r * 512 + c8 * 16) ^ ((r & 7) << 4);
      *(short8*)(wb + byte) = v;
    }
    __syncthreads();

    f32x4 acc[4];
#pragma unroll
    for (int tj = 0; tj < 4; ++tj) acc[tj] = (f32x4){0.f, 0.f, 0.f, 0.f};
#pragma unroll
    for (int ks = 0; ks < 8; ++ks) {
#pragma unroll
      for (int tj = 0; tj < 4; ++tj) {
        int rb = 16 * tj + lo;
        short8 bb = *(const short8*)(wb + ((rb * 512 + ks * 64 + g * 16) ^ ((rb & 7) << 4)));
        acc[tj] = __builtin_amdgcn_mfma_f32_16x16x32_bf16(a[ks], bb, acc[tj], 0, 0, 0);
      }
    }
    const int n0 = nt * 64;
#pragma unroll
    for (int tj = 0; tj < 4; ++tj) {
      int j = n0 + 16 * tj + lo;
      int jj = j & 255;
      float bias = (j < 256) ? bq[jj] : bk[jj];
      u16* dst = (j < 256) ? qws : kws;
      int hh = jj >> 5, d = jj & 31;
#pragma unroll
      for (int i = 0; i < 4; ++i)
        dst[mb[i] + (size_t)hh * 1600 + d] = f2bf(acc[tj][i] + bias);
    }
  }
}

// ---------------- fused attention (r3 shape + phase-ahead prefetch) ----------------
__device__ __forceinline__ void sm_store(
    f32x4 (&S)[4], const f32x4 (&bml)[4], float sl2e, float lam,
    u16* pb, int buf, int lo, int g) {
  float p[4][4];
#pragma unroll
  for (int ti = 0; ti < 4; ++ti)
#pragma unroll
    for (int i = 0; i < 4; ++i)
      p[ti][i] = exp2_fast(S[ti][i] * sl2e + bml[ti][i]);
  float t0 = (p[0][0] + p[0][1]) + (p[0][2] + p[0][3]);
  float t1 = (p[1][0] + p[1][1]) + (p[1][2] + p[1][3]);
  float t2 = (p[2][0] + p[2][1]) + (p[2][2] + p[2][3]);
  float t3 = (p[3][0] + p[3][1]) + (p[3][2] + p[3][3]);
  float sum = (t0 + t1) + (t2 + t3);
  sum += __shfl_xor(sum, 16);
  sum += __shfl_xor(sum, 32);
  float r = lam * __builtin_amdgcn_rcpf(sum);
#pragma unroll
  for (int ti = 0; ti < 4; ++ti) {
    u32x2 pk;
    pk.x = cvt_pk_bf16(p[ti][0] * r, p[ti][1] * r);
    pk.y = cvt_pk_bf16(p[ti][2] * r, p[ti][3] * r);
    *(volatile u32x2*)(pb + buf * 1152 + lo * 72 + 16 * ti + 4 * g) = pk;
  }
}

__device__ __forceinline__ void pv_acc(
    const u16* pb, int buf, const short8 (&vbS)[2][2], f32x4 (&Otj)[2],
    int lo, int g) {
#pragma unroll
  for (int ks = 0; ks < 2; ++ks) {
    u32x4 t = *(const volatile u32x4*)(pb + buf * 1152 + lo * 72 + ks * 32 + g * 8);
    short8 pa = __builtin_bit_cast(short8, t);
#pragma unroll
    for (int tjv = 0; tjv < 2; ++tjv)
      Otj[tjv] = __builtin_amdgcn_mfma_f32_16x16x32_bf16(pa, vbS[tjv][ks], Otj[tjv], 0, 0, 0);
  }
}

__global__ __launch_bounds__(256) void attn_kernel(
    const u16* __restrict__ qws, const u16* __restrict__ kws,
    const u16* __restrict__ adjb, const u16* __restrict__ matb,
    const u16* __restrict__ wab, const u16* __restrict__ wmb,
    const float* __restrict__ bap, const float* __restrict__ bmp,
    const float* __restrict__ maskv,
    const float* __restrict__ lambdas, float* __restrict__ out) {
  __shared__ u16 smem[4][2304];     // per wave 4608B: kT[32][72] overlaid by P dbuf
  const int tid = threadIdx.x;
  const int w = tid >> 6, l = tid & 63, lo = l & 15, g = l >> 4;
  const int bh = blockIdx.x * 4 + w;
  const int b = bh >> 3, h = bh & 7;
  u16* sh = smem[w];

  const u16* kbase = kws + (size_t)bh * 1600;
  const u16* qbase = qws + (size_t)bh * 1600;

  // ---- issue: k rows (for kT), P1 fragments, P2 B-fragments ----
  short8 kr[4];
#pragma unroll
  for (int ch = 0; ch < 4; ++ch)
    kr[ch] = *(const short8*)(kbase + (size_t)l * 32 + ch * 8);   // no l<50 mask:
    // garbage rows are finite; P is exactly 0 for m>=50, so PV is unaffected.
  short8 af1[4], qf1[4];
#pragma unroll
  for (int ti = 0; ti < 4; ++ti)
    af1[ti] = *(const short8*)(kbase + (size_t)(lo + 16 * ti) * 32 + g * 8);
#pragma unroll
  for (int tj = 0; tj < 4; ++tj)
    qf1[tj] = *(const short8*)(qbase + (size_t)(lo + 16 * tj) * 32 + g * 8);
  const u16* bB2 = adjb + (size_t)b * 3200;
  short8 bf2[4][2];
#pragma unroll
  for (int tj = 0; tj < 4; ++tj)
#pragma unroll
    for (int ks = 0; ks < 2; ++ks)
      bf2[tj][ks] = *(const short8*)(bB2 + (size_t)(lo + 16 * tj) * 64 + ks * 32 + g * 8);
  __builtin_amdgcn_sched_barrier(0);   // pin: all the above issue before compute

  // softmax(lambdas[h])
  float la = lambdas[h * 3 + 0], lb = lambdas[h * 3 + 1], lc = lambdas[h * 3 + 2];
  float lmx = fmaxf(la, fmaxf(lb, lc));
  float e0 = __expf(la - lmx), e1 = __expf(lb - lmx), e2 = __expf(lc - lmx);
  float einv = 1.f / (e0 + e1 + e2);
  float lam0 = e0 * einv, lam1 = e1 * einv, lam2 = e2 * einv;

  // ---- stage kT = V^T [32 d][72 m] (volatile scalar writes) ----
#pragma unroll
  for (int ch = 0; ch < 4; ++ch)
#pragma unroll
    for (int jj = 0; jj < 8; ++jj)
      *(volatile u16*)(sh + (ch * 8 + jj) * 72 + l) = (u16)kr[ch][jj];
  // hoist V^T fragments (kT region is reused as P afterwards)
  short8 vb[2][2];
#pragma unroll
  for (int tjv = 0; tjv < 2; ++tjv)
#pragma unroll
    for (int ks = 0; ks < 2; ++ks) {
      u32x4 t = *(const volatile u32x4*)(sh + (lo + 16 * tjv) * 72 + ks * 32 + g * 8);
      vb[tjv][ks] = __builtin_bit_cast(short8, t);
    }

  f32x4 O[4][2];
#pragma unroll
  for (int tj = 0; tj < 4; ++tj)
#pragma unroll
    for (int tjv = 0; tjv < 2; ++tjv) O[tj][tjv] = (f32x4){0.f, 0.f, 0.f, 0.f};

  // ---- phase 1: S^T = K·Q^T, scale (1/16)·log2e ----
  {
    f32x4 bml[4];
#pragma unroll
    for (int ti = 0; ti < 4; ++ti)
      bml[ti] = *(const f32x4*)(maskv + 16 * ti + 4 * g);
#pragma unroll
    for (int tj = 0; tj < 4; ++tj) {
      f32x4 S[4];
#pragma unroll
      for (int ti = 0; ti < 4; ++ti) S[ti] = (f32x4){0.f, 0.f, 0.f, 0.f};
#pragma unroll
      for (int ti = 0; ti < 4; ++ti)
        S[ti] = __builtin_amdgcn_mfma_f32_16x16x32_bf16(af1[ti], qf1[tj], S[ti], 0, 0, 0);
      sm_store(S, bml, 0.0625f * L2E, lam0, sh, tj & 1, lo, g);
      pv_acc(sh, tj & 1, vb, O[tj], lo, g);
    }
  }

  // ---- issue phase-3 B-fragments before phase-2 compute ----
  const u16* bB3 = matb + (size_t)b * 3200;
  short8 bf3[4][2];
#pragma unroll
  for (int tj = 0; tj < 4; ++tj)
#pragma unroll
    for (int ks = 0; ks < 2; ++ks)
      bf3[tj][ks] = *(const short8*)(bB3 + (size_t)(lo + 16 * tj) * 64 + ks * 32 + g * 8);
  __builtin_amdgcn_sched_barrier(0);

  // ---- phase 2: adj transform ----
  {
    const u16* aBase = wab + (size_t)h * 3200;
    short8 afw[4][2];
#pragma unroll
    for (int ti = 0; ti < 4; ++ti)
#pragma unroll
      for (int ks = 0; ks < 2; ++ks)
        afw[ti][ks] = *(const short8*)(aBase + (size_t)(lo + 16 * ti) * 64 + ks * 32 + g * 8);
    f32x4 bml[4];
#pragma unroll
    for (int ti = 0; ti < 4; ++ti)
      bml[ti] = *(const f32x4*)(bap + h * 64 + 16 * ti + 4 * g);
#pragma unroll
    for (int tj = 0; tj < 4; ++tj) {
      f32x4 S[4];
#pragma unroll
      for (int ti = 0; ti < 4; ++ti) S[ti] = (f32x4){0.f, 0.f, 0.f, 0.f};
#pragma unroll
      for (int ti = 0; ti < 4; ++ti)
        S[ti] = __builtin_amdgcn_mfma_f32_16x16x32_bf16(afw[ti][0], bf2[tj][0], S[ti], 0, 0, 0);
#pragma unroll
      for (int ti = 0; ti < 4; ++ti)
        S[ti] = __builtin_amdgcn_mfma_f32_16x16x32_bf16(afw[ti][1], bf2[tj][1], S[ti], 0, 0, 0);
      sm_store(S, bml, L2E, lam1, sh, tj & 1, lo, g);
      pv_acc(sh, tj & 1, vb, O[tj], lo, g);
    }
  }
  // ---- phase 3: matrix transform ----
  {
    const u16* aBase = wmb + (size_t)h * 3200;
    short8 afw[4][2];
#pragma unroll
    for (int ti = 0; ti < 4; ++ti)
#pragma unroll
      for (int ks = 0; ks < 2; ++ks)
        afw[ti][ks] = *(const short8*)(aBase + (size_t)(lo + 16 * ti) * 64 + ks * 32 + g * 8);
    f32x4 bml[4];
#pragma unroll
    for (int ti = 0; ti < 4; ++ti)
      bml[ti] = *(const f32x4*)(bmp + h * 64 + 16 * ti + 4 * g);
#pragma unroll
    for (int tj = 0; tj < 4; ++tj) {
      f32x4 S[4];
#pragma unroll
      for (int ti = 0; ti < 4; ++ti) S[ti] = (f32x4){0.f, 0.f, 0.f, 0.f};
#pragma unroll
      for (int ti = 0; ti < 4; ++ti)
        S[ti] = __builtin_amdgcn_mfma_f32_16x16x32_bf16(afw[ti][0], bf3[tj][0], S[ti], 0, 0, 0);
#pragma unroll
      for (int ti = 0; ti < 4; ++ti)
        S[ti] = __builtin_amdgcn_mfma_f32_16x16x32_bf16(afw[ti][1], bf3[tj][1], S[ti], 0, 0, 0);
      sm_store(S, bml, L2E, lam2, sh, tj & 1, lo, g);
      pv_acc(sh, tj & 1, vb, O[tj], lo, g);
    }
  }

  // ---- epilogue: out[b][n][h*32+d], f32 ----
  float* ob = out + (size_t)b * 12800 + h * 32;
#pragma unroll
  for (int tj = 0; tj < 4; ++tj)
#pragma unroll
    for (int i = 0; i < 4; ++i) {
      int n = 16 * tj + 4 * g + i;
      if (n < 50) {
#pragma unroll
        for (int tjv = 0; tjv < 2; ++tjv)
          ob[(size_t)n * 256 + 16 * tjv + lo] = O[tj][tjv][i];
      }
    }
}

extern "C" void kernel_launch(void* const* d_in, const int* in_sizes, int n_in,
                              void* d_out, int out_size, void* d_ws, size_t ws_size,
                              hipStream_t stream) {
  const float* x       = (const float*)d_in[0];
  const float* adj     = (const float*)d_in[1];
  const float* mat     = (const float*)d_in[2];
  const float* Wq      = (const float*)d_in[3];
  const float* bq      = (const float*)d_in[4];
  const float* Wk      = (const float*)d_in[5];
  const float* bk      = (const float*)d_in[6];
  const float* Wa      = (const float*)d_in[7];
  const float* ba      = (const float*)d_in[8];
  const float* Wm      = (const float*)d_in[9];
  const float* bm      = (const float*)d_in[10];
  const float* lambdas = (const float*)d_in[11];
  float* out = (float*)d_out;

  char* ws = (char*)d_ws;
  u16* wqk    = (u16*)ws; ws += (size_t)512 * 256 * 2;
  u16* wab    = (u16*)ws; ws += (size_t)416 * 64 * 2;
  u16* wmb    = (u16*)ws; ws += (size_t)416 * 64 * 2;
  float* bap  = (float*)ws; ws += (size_t)512 * 4;
  float* bmp  = (float*)ws; ws += (size_t)512 * 4;
  float* mskv = (float*)ws; ws += (size_t)64 * 4;
  u16* adjb   = (u16*)ws; ws += (size_t)102416 * 64 * 2;
  u16* matb   = (u16*)ws; ws += (size_t)102416 * 64 * 2;
  u16* qws    = (u16*)ws; ws += (size_t)819264 * 32 * 2;  // 16384*50 + 64 slack
  u16* kws    = (u16*)ws; ws += (size_t)819264 * 32 * 2;

  cast_all<<<2217, 256, 0, stream>>>(adj, mat, Wq, Wk, Wa, Wm, ba, bm,
                                     adjb, matb, wqk, wab, wmb,
                                     bap, bmp, mskv, qws, kws);
  proj_kernel<<<1600, 256, 0, stream>>>(x, wqk, bq, bk, qws, kws);
  attn_kernel<<<4096, 256, 0, stream>>>(qws, kws, adjb, matb, wab, wmb,
                                        bap, bmp, mskv, lambdas, out);
}